// Round 3
// baseline (81.997 us; speedup 1.0000x reference)
//
#include <hip/hip_runtime.h>
#include <hip/hip_bf16.h>

#define NN 4096
#define DD 512

// ---- fused3 geometry (256^2 tile, 8 waves, BK=32, triple-buffered) ----
#define BM2 256
#define BK2 32
#define T2  16                       // NN/BM2
#define TRI2 (T2*(T2+1)/2)           // 136
#define NBLK3 (T2*T2 + 2*TRI2)       // 528
#define BUFU 16384                   // ushorts per LDS buffer (A 8192 + B 8192)

// ---- fallback geometry (round-1) ----
#define BM 128
#define BK 32
#define LDP 40
#define TILES 32
#define TRI (TILES*(TILES+1)/2)

typedef __attribute__((ext_vector_type(8))) short short8v;
typedef __attribute__((ext_vector_type(4))) short short4v;
typedef __attribute__((ext_vector_type(4))) float f32x4;

static __device__ __forceinline__ short f2bf(float f) {
    union { float f; unsigned u; } a; a.f = f;
    unsigned r = a.u + 0x7FFFu + ((a.u >> 16) & 1u);
    return (short)(r >> 16);
}

static __device__ __forceinline__ void stage16(const void* g, void* l) {
    __builtin_amdgcn_global_load_lds(
        (const __attribute__((address_space(1))) unsigned int*)g,
        (__attribute__((address_space(3))) unsigned int*)l, 16, 0, 0);
}

// ---------- prep: fp32 -> bf16 ws + row norms ----------
__global__ void prep_kernel(const float* __restrict__ x, const float* __restrict__ y,
                            ushort* __restrict__ bx, ushort* __restrict__ by,
                            float* __restrict__ nx, float* __restrict__ ny) {
    int wid  = (blockIdx.x * blockDim.x + threadIdx.x) >> 6;   // 0..8191
    int lane = threadIdx.x & 63;
    bool isx = wid < NN;
    const float* src = isx ? x : y;
    ushort* dst = isx ? bx : by;
    int row = wid & (NN - 1);
    const float4* p = (const float4*)(src + (size_t)row * DD);
    float s = 0.f;
    #pragma unroll
    for (int i = 0; i < 2; ++i) {
        float4 v = p[lane + 64 * i];
        s += v.x * v.x + v.y * v.y + v.z * v.z + v.w * v.w;
        short4v h = { f2bf(v.x), f2bf(v.y), f2bf(v.z), f2bf(v.w) };
        *(short4v*)(dst + (size_t)row * DD + 4 * (lane + 64 * i)) = h;
    }
    #pragma unroll
    for (int off = 32; off > 0; off >>= 1) s += __shfl_down(s, off);
    if (lane == 0) (isx ? nx : ny)[row] = s;
}

// decode for 256-tiles
static __device__ __forceinline__ void decode_tile2(int bid, int& p, int& ti, int& tj, float& w) {
    w = 1.f;
    if (bid < T2 * T2) {
        p = 2; ti = bid >> 4; tj = bid & (T2 - 1);
    } else {
        int u = bid - T2 * T2;
        p = 0;
        if (u >= TRI2) { p = 1; u -= TRI2; }
        int a = 0;
        while (u >= T2 - a) { u -= T2 - a; ++a; }
        ti = a; tj = a + u;
        if (ti != tj) w = 2.f;
    }
}

// ---------- fused3: 256^2 tile, 2-phase/K-tile, counted vmcnt, swizzled LDS ----------
__global__ void __launch_bounds__(512, 2)
fused3_kernel(const ushort* __restrict__ bx, const ushort* __restrict__ by,
              const float* __restrict__ nx, const float* __restrict__ ny,
              float* __restrict__ out) {
    __shared__ __align__(16) ushort lds[3 * BUFU];   // 96 KiB
    __shared__ float wsum[8];

    int p, ti, tj; float w;
    decode_tile2(blockIdx.x, p, ti, tj, w);

    const ushort* PB = (p == 1) ? by : bx;
    const ushort* QB = (p == 0) ? bx : by;
    const float*  NA = (p == 1) ? ny : nx;
    const float*  NB = (p == 0) ? nx : ny;

    const int t    = threadIdx.x;
    const int lane = t & 63;
    const int wv   = t >> 6;          // 0..7
    const int wm   = wv >> 2;         // 0..1  (M half)
    const int wn   = wv & 3;          // 0..3  (N quarter)
    const int fr   = lane & 15;

    const ushort* Ag = PB + (size_t)ti * BM2 * DD;
    const ushort* Bg = QB + (size_t)tj * BM2 * DD;

    // staging: wave wv covers segments {2wv, 2wv+1} of 16 (16 rows each).
    // LDS dest is linear (seg*1024B + lane*16B); global source column-block is
    // inverse-swizzled: cb_glob = (lane&3) ^ ((lane>>3)&3).
    const int srow = lane >> 2;                              // row within segment
    const int scol = ((lane & 3) ^ ((lane >> 3) & 3)) * 8;   // ushort offset
    // read-side swizzle: for row r (base multiple of 16 + fr), cb' = cb ^ ((fr>>1)&3)
    const int cbs = (((lane >> 4) ^ ((lane >> 1) & 3))) * 8; // ushort offset

    f32x4 acc[8][4];
    #pragma unroll
    for (int m = 0; m < 8; ++m)
        #pragma unroll
        for (int n = 0; n < 4; ++n)
            acc[m][n] = (f32x4){0.f, 0.f, 0.f, 0.f};

    // prologue: stage K-tiles 0 and 1 (A then B per tile: 4 loads/wave/tile)
    #pragma unroll
    for (int kt = 0; kt < 2; ++kt) {
        ushort* LA = lds + kt * BUFU;
        #pragma unroll
        for (int i = 0; i < 2; ++i) {
            int s = wv * 2 + i;
            stage16(Ag + (size_t)(s * 16 + srow) * DD + kt * BK2 + scol, LA + s * 512);
        }
        #pragma unroll
        for (int i = 0; i < 2; ++i) {
            int s = wv * 2 + i;
            stage16(Bg + (size_t)(s * 16 + srow) * DD + kt * BK2 + scol, LA + 8192 + s * 512);
        }
    }
    asm volatile("s_waitcnt vmcnt(4)" ::: "memory");   // tile 0 landed, tile 1 in flight
    __builtin_amdgcn_s_barrier();

    int cur = 0;
    for (int kt = 0; kt < T2; ++kt) {
        ushort* LA = lds + cur * BUFU;
        ushort* LB = LA + 8192;
        int b2 = cur + 2; if (b2 >= 3) b2 -= 3;
        const bool more = (kt + 2 < T2);
        short8v af[4], bfr[4];

        // ---- phase 0: B frags + A frags (mq=0); stage A of kt+2 ----
        #pragma unroll
        for (int n = 0; n < 4; ++n)
            bfr[n] = *(const short8v*)(&LB[(wn * 64 + n * 16 + fr) * BK2 + cbs]);
        #pragma unroll
        for (int m = 0; m < 4; ++m)
            af[m] = *(const short8v*)(&LA[(wm * 128 + m * 16 + fr) * BK2 + cbs]);
        if (more) {
            ushort* DA = lds + b2 * BUFU;
            #pragma unroll
            for (int i = 0; i < 2; ++i) {
                int s = wv * 2 + i;
                stage16(Ag + (size_t)(s * 16 + srow) * DD + (kt + 2) * BK2 + scol, DA + s * 512);
            }
        }
        __builtin_amdgcn_s_barrier();
        asm volatile("s_waitcnt lgkmcnt(0)" ::: "memory");
        __builtin_amdgcn_s_setprio(1);
        #pragma unroll
        for (int m = 0; m < 4; ++m)
            #pragma unroll
            for (int n = 0; n < 4; ++n)
                acc[m][n] = __builtin_amdgcn_mfma_f32_16x16x32_bf16(af[m], bfr[n], acc[m][n], 0, 0, 0);
        __builtin_amdgcn_s_setprio(0);
        __builtin_amdgcn_s_barrier();

        // ---- phase 1: A frags (mq=1), B reused; stage B of kt+2 ----
        #pragma unroll
        for (int m = 0; m < 4; ++m)
            af[m] = *(const short8v*)(&LA[(wm * 128 + 64 + m * 16 + fr) * BK2 + cbs]);
        if (more) {
            ushort* DB = lds + b2 * BUFU + 8192;
            #pragma unroll
            for (int i = 0; i < 2; ++i) {
                int s = wv * 2 + i;
                stage16(Bg + (size_t)(s * 16 + srow) * DD + (kt + 2) * BK2 + scol, DB + s * 512);
            }
        }
        __builtin_amdgcn_s_barrier();
        asm volatile("s_waitcnt lgkmcnt(0)" ::: "memory");
        __builtin_amdgcn_s_setprio(1);
        #pragma unroll
        for (int m = 0; m < 4; ++m)
            #pragma unroll
            for (int n = 0; n < 4; ++n)
                acc[4 + m][n] = __builtin_amdgcn_mfma_f32_16x16x32_bf16(af[m], bfr[n], acc[4 + m][n], 0, 0, 0);
        __builtin_amdgcn_s_setprio(0);
        // counted wait: tile kt+1's 4 loads retired; kt+2's (if any) stay in flight
        if (kt < T2 - 2) asm volatile("s_waitcnt vmcnt(4)" ::: "memory");
        else             asm volatile("s_waitcnt vmcnt(0)" ::: "memory");
        __builtin_amdgcn_s_barrier();
        cur = cur + 1; if (cur >= 3) cur -= 3;
    }

    // ---- epilogue ----
    float nbv[4];
    #pragma unroll
    for (int n = 0; n < 4; ++n)
        nbv[n] = NB[tj * BM2 + wn * 64 + n * 16 + fr];

    const int rbase = ((lane >> 4) << 2);
    float local = 0.f;
    #pragma unroll
    for (int mi = 0; mi < 8; ++mi) {
        float4 na4 = *(const float4*)(&NA[ti * BM2 + wm * 128 + mi * 16 + rbase]);
        float nav[4] = { na4.x, na4.y, na4.z, na4.w };
        #pragma unroll
        for (int n = 0; n < 4; ++n) {
            #pragma unroll
            for (int rr = 0; rr < 4; ++rr) {
                int row = wm * 128 + mi * 16 + rbase + rr;
                int col = wn * 64 + n * 16 + fr;
                int gr = ti * BM2 + row, gc = tj * BM2 + col;
                float g  = acc[mi][n][rr];
                float d2 = fmaxf(nav[rr] + nbv[n] - 2.f * g, 0.f);
                float e  = __expf(-d2);
                if (p == 2) {
                    float diff = g - ((gr == gc) ? 1.f : 0.f);
                    local += diff * diff - 2.f * e;
                } else {
                    local += w * e;
                }
            }
        }
    }
    #pragma unroll
    for (int off = 32; off > 0; off >>= 1) local += __shfl_down(local, off);
    if (lane == 0) wsum[wv] = local;
    __syncthreads();
    if (t == 0) {
        float s = 0.f;
        #pragma unroll
        for (int i = 0; i < 8; ++i) s += wsum[i];
        atomicAdd(out, s * (1.f / ((float)NN * (float)NN)));
    }
}

// ---------- fallback path (round-1, used only if ws too small) ----------
static __device__ __forceinline__ void decode_tile(int bid, int& p, int& ti, int& tj, float& w) {
    w = 1.f;
    if (bid < TILES * TILES) {
        p = 2; ti = bid >> 5; tj = bid & (TILES - 1);
    } else {
        int u = bid - TILES * TILES;
        p = 0;
        if (u >= TRI) { p = 1; u -= TRI; }
        int a = 0;
        while (u >= TILES - a) { u -= TILES - a; ++a; }
        ti = a; tj = a + u;
        if (ti != tj) w = 2.f;
    }
}

__global__ void norms_kernel(const float* __restrict__ x, const float* __restrict__ y,
                             float* __restrict__ nx, float* __restrict__ ny) {
    int wid  = (blockIdx.x * blockDim.x + threadIdx.x) >> 6;
    int lane = threadIdx.x & 63;
    const float* src = (wid < NN) ? x : y;
    int row = wid & (NN - 1);
    const float4* p = (const float4*)(src + (size_t)row * DD);
    float s = 0.f;
    #pragma unroll
    for (int i = 0; i < 2; ++i) {
        float4 v = p[lane + 64 * i];
        s += v.x * v.x + v.y * v.y + v.z * v.z + v.w * v.w;
    }
    #pragma unroll
    for (int off = 32; off > 0; off >>= 1) s += __shfl_down(s, off);
    if (lane == 0) ((wid < NN) ? nx : ny)[row] = s;
}

__global__ void __launch_bounds__(256)
fused_kernel(const float* __restrict__ x, const float* __restrict__ y,
             const float* __restrict__ nx, const float* __restrict__ ny,
             float* __restrict__ out) {
    __shared__ __align__(16) short As[BM * LDP];
    __shared__ __align__(16) short Bs[BM * LDP];
    __shared__ float wsum[4];

    int p, ti, tj; float w;
    decode_tile(blockIdx.x, p, ti, tj, w);
    const float* P  = (p == 1) ? y  : x;
    const float* Q  = (p == 0) ? x  : y;
    const float* NA = (p == 1) ? ny : nx;
    const float* NB = (p == 0) ? nx : ny;

    const int t    = threadIdx.x;
    const int lane = t & 63;
    const int wvid = t >> 6;
    const int wm = wvid >> 1, wn = wvid & 1;

    f32x4 acc[4][4];
    #pragma unroll
    for (int m = 0; m < 4; ++m)
        #pragma unroll
        for (int n = 0; n < 4; ++n)
            acc[m][n] = (f32x4){0.f, 0.f, 0.f, 0.f};

    const int srow = t >> 3;
    const int scol = (t & 7) * 4;
    const size_t baseA = (size_t)(ti * BM) * DD;
    const size_t baseB = (size_t)(tj * BM) * DD;

    for (int kt = 0; kt < DD; kt += BK) {
        #pragma unroll
        for (int s = 0; s < 4; ++s) {
            int r = s * 32 + srow;
            float4 va = *(const float4*)(P + baseA + (size_t)r * DD + kt + scol);
            float4 vb = *(const float4*)(Q + baseB + (size_t)r * DD + kt + scol);
            short4v ha = { f2bf(va.x), f2bf(va.y), f2bf(va.z), f2bf(va.w) };
            short4v hb = { f2bf(vb.x), f2bf(vb.y), f2bf(vb.z), f2bf(vb.w) };
            *(short4v*)(&As[r * LDP + scol]) = ha;
            *(short4v*)(&Bs[r * LDP + scol]) = hb;
        }
        __syncthreads();

        short8v af[4], bfr[4];
        const int kc = (lane >> 4) * 8;
        #pragma unroll
        for (int m = 0; m < 4; ++m)
            af[m] = *(const short8v*)(&As[(wm * 64 + m * 16 + (lane & 15)) * LDP + kc]);
        #pragma unroll
        for (int n = 0; n < 4; ++n)
            bfr[n] = *(const short8v*)(&Bs[(wn * 64 + n * 16 + (lane & 15)) * LDP + kc]);
        #pragma unroll
        for (int m = 0; m < 4; ++m)
            #pragma unroll
            for (int n = 0; n < 4; ++n)
                acc[m][n] = __builtin_amdgcn_mfma_f32_16x16x32_bf16(af[m], bfr[n], acc[m][n], 0, 0, 0);
        __syncthreads();
    }

    float local = 0.f;
    #pragma unroll
    for (int m = 0; m < 4; ++m) {
        #pragma unroll
        for (int n = 0; n < 4; ++n) {
            #pragma unroll
            for (int r = 0; r < 4; ++r) {
                int row = wm * 64 + m * 16 + ((lane >> 4) << 2) + r;
                int col = wn * 64 + n * 16 + (lane & 15);
                int gr = ti * BM + row, gc = tj * BM + col;
                float g  = acc[m][n][r];
                float d2 = fmaxf(NA[gr] + NB[gc] - 2.f * g, 0.f);
                float e  = __expf(-d2);
                if (p == 2) {
                    float diff = g - ((gr == gc) ? 1.f : 0.f);
                    local += diff * diff - 2.f * e;
                } else {
                    local += w * e;
                }
            }
        }
    }
    #pragma unroll
    for (int off = 32; off > 0; off >>= 1) local += __shfl_down(local, off);
    if (lane == 0) wsum[wvid] = local;
    __syncthreads();
    if (t == 0) {
        float s = (wsum[0] + wsum[1]) + (wsum[2] + wsum[3]);
        atomicAdd(out, s * (1.f / ((float)NN * (float)NN)));
    }
}

extern "C" void kernel_launch(void* const* d_in, const int* in_sizes, int n_in,
                              void* d_out, int out_size, void* d_ws, size_t ws_size,
                              hipStream_t stream) {
    const float* x = (const float*)d_in[0];
    const float* y = (const float*)d_in[1];
    float* out = (float*)d_out;

    hipMemsetAsync(d_out, 0, sizeof(float), stream);

    const size_t need = (size_t)2 * NN * DD * sizeof(ushort) + (size_t)2 * NN * sizeof(float);
    if (ws_size >= need) {
        ushort* bx = (ushort*)d_ws;
        ushort* by = bx + (size_t)NN * DD;
        float*  nx = (float*)(by + (size_t)NN * DD);
        float*  ny = nx + NN;
        prep_kernel<<<dim3(2048), dim3(256), 0, stream>>>(x, y, bx, by, nx, ny);
        fused3_kernel<<<dim3(NBLK3), dim3(512), 0, stream>>>(bx, by, nx, ny, out);
    } else {
        float* nx = (float*)d_ws;
        float* ny = nx + NN;
        norms_kernel<<<dim3(2048), dim3(256), 0, stream>>>(x, y, nx, ny);
        fused_kernel<<<dim3(TILES * TILES + 2 * TRI), dim3(256), 0, stream>>>(x, y, nx, ny, out);
    }
}